// Round 1
// baseline (1798.337 us; speedup 1.0000x reference)
//
#include <hip/hip_runtime.h>

#define HH 512
#define WW 512
#define NPIX (HH * WW)          // 262144
#define NIMG 16
#define KPTS 1024
#define NWORDS (NPIX / 64)      // 4096 u64 mask words per image

// ---------------------------------------------------------------------------
// Kernel 1: binarize + uniform LBP (P=8,R=1) + ballot-pack mask bits
// ---------------------------------------------------------------------------
__global__ void lbp_kernel(const float* __restrict__ mo,
                           const float* __restrict__ lb,
                           unsigned long long* __restrict__ maskbits) {
#pragma clang fp contract(off)
    int m = blockIdx.y;                    // image 0..15: even=pred, odd=mask
    int pix = blockIdx.x * blockDim.x + threadIdx.x;   // 0..262143
    int r = pix >> 9, c = pix & 511;
    int sample = m >> 1;
    const float* img = (m & 1) ? (lb + sample * NPIX) : (mo + sample * NPIX);
    float thr = (m & 1) ? 0.5f : 0.0f;     // sigmoid(x)>0.5 <=> x>0

    float center = img[pix] > thr ? 1.0f : 0.0f;

    const float A = 0.70710678f;           // np.round(sin/cos, 8)
    const float drs[8] = {0.f, -A, -1.f, -A, 0.f,  A, 1.f, A};
    const float dcs[8] = {1.f,  A,  0.f, -A, -1.f, -A, 0.f, A};

    unsigned bb = 0u;
#pragma unroll
    for (int k = 0; k < 8; k++) {
        float rr = (float)r + drs[k];
        float cc = (float)c + dcs[k];
        float r0 = floorf(rr), c0 = floorf(cc);
        float fr = rr - r0,   fc = cc - c0;
        int r0i = (int)r0; r0i = max(0, min(HH - 1, r0i));
        int c0i = (int)c0; c0i = max(0, min(WW - 1, c0i));
        int r1i = min(HH - 1, r0i + 1);
        int c1i = min(WW - 1, c0i + 1);
        float g00 = img[r0i * WW + c0i] > thr ? 1.0f : 0.0f;
        float g01 = img[r0i * WW + c1i] > thr ? 1.0f : 0.0f;
        float g10 = img[r1i * WW + c0i] > thr ? 1.0f : 0.0f;
        float g11 = img[r1i * WW + c1i] > thr ? 1.0f : 0.0f;
        float s1 = (1.0f - fc) * g00 + fc * g01;
        float s2 = (1.0f - fc) * g10 + fc * g11;
        float smp = (1.0f - fr) * s1 + fr * s2;
        if (smp - center >= 0.0f) bb |= (1u << k);
    }
    // changes = circular transitions; s = popcount; uniform: lbp = s else 9
    unsigned rol = ((bb << 1) | (bb >> 7)) & 0xFFu;
    int changes = __popc(bb ^ rol);
    int s = __popc(bb);
    bool maskbit = (changes <= 2) && (s < 5);   // lbp < THR(=5)

    unsigned long long w = __ballot(maskbit);
    if ((threadIdx.x & 63) == 0)
        maskbits[m * NWORDS + (pix >> 6)] = w;
}

// ---------------------------------------------------------------------------
// Kernel 2: stable row-major compaction to K=1024 packed points per image
// pts entry: (r<<16)|c ; zero-padded (== reference's valid*coords semantics)
// ---------------------------------------------------------------------------
__global__ void select_kernel(const unsigned long long* __restrict__ maskbits,
                              unsigned* __restrict__ ptsG) {
    __shared__ unsigned sc[256];
    int m = blockIdx.x, tid = threadIdx.x;

    for (int i = tid; i < KPTS; i += 256) ptsG[m * KPTS + i] = 0u;
    __syncthreads();

    unsigned running = 0;
    for (int ch = 0; ch < 16; ch++) {
        int w = ch * 256 + tid;
        unsigned long long word = maskbits[m * NWORDS + w];
        unsigned cnt = (unsigned)__popcll(word);
        sc[tid] = cnt;
        __syncthreads();
        for (int off = 1; off < 256; off <<= 1) {
            unsigned v = (tid >= off) ? sc[tid - off] : 0u;
            __syncthreads();
            sc[tid] += v;
            __syncthreads();
        }
        unsigned incl = sc[tid];
        unsigned total = sc[255];
        unsigned rank = running + incl - cnt;   // exclusive prefix
        while (word) {
            int b = __builtin_ctzll(word);
            word &= word - 1;
            if (rank < (unsigned)KPTS) {
                unsigned p = (unsigned)(w * 64 + b);
                unsigned rr = p >> 9, cc = p & 511u;
                ptsG[m * KPTS + rank] = (rr << 16) | cc;
            }
            rank++;
        }
        running += total;
        __syncthreads();
    }
}

// ---------------------------------------------------------------------------
// Kernel 3: one single-wave block per image: Prim's MST (exact integer keys)
// + fused per-edge (D_self - D_other)^2 accumulation. partials[m]=sqrt(S).
// key = (d2<<10)|idx : unsigned-min reduce == argmin with first-index ties;
// in-tree = 0xFFFFFFFF : signed '<' in update == upd & ~in_tree.
// ---------------------------------------------------------------------------
__global__ __launch_bounds__(64) void mst_kernel(const unsigned* __restrict__ ptsG,
                                                 float* __restrict__ partials) {
    __shared__ unsigned ldsO[KPTS];
    int lane = threadIdx.x;          // 0..63
    int m = blockIdx.x;
    int partner = m ^ 1;

#pragma unroll
    for (int s = 0; s < 16; s++)
        ldsO[s * 64 + lane] = ptsG[partner * KPTS + s * 64 + lane];

    unsigned key[16], srcv[16], pay[16];
    int rr[16], cch[16];

    unsigned p0 = ptsG[m * KPTS];            // point 0 (uniform load)
    int r0p = (int)(p0 >> 16), c0p = (int)(p0 & 0xFFFFu);

#pragma unroll
    for (int s = 0; s < 16; s++) {
        unsigned p = ptsG[m * KPTS + s * 64 + lane];
        int r = (int)(p >> 16), c = (int)(p & 0xFFFFu);
        rr[s] = r; cch[s] = c;
        pay[s] = (unsigned)((r << 9) | c);   // static coord payload
        srcv[s] = 0u;                        // src init = 0
        int dr = r - r0p, dc = c - c0p;
        int d2 = __mul24(dr, dr) + __mul24(dc, dc);
        key[s] = ((unsigned)d2 << 10) | (unsigned)(s * 64 + lane);
    }
    if (lane == 0) key[0] = 0xFFFFFFFFu;     // in_tree[0] = True
    __syncthreads();

    double S = 0.0;
    for (int it = 0; it < KPTS - 1; it++) {
        // ---- in-lane tournament over 16 slots (key + payload) ----
        unsigned tk[8], tp[8];
#pragma unroll
        for (int s = 0; s < 8; s++) {
            bool lt = key[2 * s + 1] < key[2 * s];
            tk[s] = lt ? key[2 * s + 1] : key[2 * s];
            tp[s] = lt ? pay[2 * s + 1] : pay[2 * s];
        }
#pragma unroll
        for (int off = 4; off >= 1; off >>= 1) {
#pragma unroll
            for (int s = 0; s < 4; s++) {
                if (s < off) {
                    bool lt = tk[s + off] < tk[s];
                    tk[s] = lt ? tk[s + off] : tk[s];
                    tp[s] = lt ? tp[s + off] : tp[s];
                }
            }
        }
        unsigned rk = tk[0], rp = tp[0];
        // ---- wave-64 butterfly min (key, payload) ----
#pragma unroll
        for (int d = 1; d < 64; d <<= 1) {
            unsigned ok = (unsigned)__shfl_xor((int)rk, d, 64);
            unsigned op = (unsigned)__shfl_xor((int)rp, d, 64);
            bool lt = ok < rk;
            rk = lt ? ok : rk;
            rp = lt ? op : rp;
        }
        unsigned wk = (unsigned)__builtin_amdgcn_readfirstlane((int)rk);
        unsigned wp = (unsigned)__builtin_amdgcn_readfirstlane((int)rp);

        unsigned j   = wk & 1023u;
        unsigned d2p = wk >> 10;
        int rj = (int)((wp >> 9) & 511u), cj = (int)(wp & 511u);

        // ---- src[j] broadcast: uniform slot switch + readlane ----
        unsigned wslot = j >> 6, wlane = j & 63u;
        unsigned sv;
        switch (wslot) {
            case 0:  sv = srcv[0];  break;  case 1:  sv = srcv[1];  break;
            case 2:  sv = srcv[2];  break;  case 3:  sv = srcv[3];  break;
            case 4:  sv = srcv[4];  break;  case 5:  sv = srcv[5];  break;
            case 6:  sv = srcv[6];  break;  case 7:  sv = srcv[7];  break;
            case 8:  sv = srcv[8];  break;  case 9:  sv = srcv[9];  break;
            case 10: sv = srcv[10]; break;  case 11: sv = srcv[11]; break;
            case 12: sv = srcv[12]; break;  case 13: sv = srcv[13]; break;
            case 14: sv = srcv[14]; break;  default: sv = srcv[15]; break;
        }
        unsigned srcj = (unsigned)__builtin_amdgcn_readlane((int)sv, (int)wlane);

        // ---- edge contribution: (D_self[e] - D_other[e])^2 ----
        unsigned pj = ldsO[j], ps = ldsO[srcj];
        int drm = (int)(pj >> 16) - (int)(ps >> 16);
        int dcm = (int)(pj & 0xFFFFu) - (int)(ps & 0xFFFFu);
        int dm2 = __mul24(drm, drm) + __mul24(dcm, dcm);
        float Dp = __fsqrt_rn((float)d2p);
        float Dm = __fsqrt_rn((float)dm2);
        float diff = Dp - Dm;
        S += (double)diff * (double)diff;

        // ---- decrease-key update + remove j ----
        bool laneHit = (lane == (int)wlane);
#pragma unroll
        for (int s = 0; s < 16; s++) {
            int dr = rr[s] - rj, dc = cch[s] - cj;
            int d2 = __mul24(dr, dr) + __mul24(dc, dc);
            unsigned nk = ((((unsigned)d2 << 4) | (unsigned)s) << 6) | (unsigned)lane;
            bool upd = (int)nk < (int)key[s];   // signed: in-tree (-1) wins
            key[s]  = upd ? nk : key[s];
            srcv[s] = upd ? j  : srcv[s];
            if (wslot == (unsigned)s)
                key[s] = laneHit ? 0xFFFFFFFFu : key[s];
        }
    }
    if (lane == 0) partials[m] = (float)sqrt(S);
}

// ---------------------------------------------------------------------------
// Kernel 4: loss = 0.1 * sum(sqrt(S_m)) / 8  (deterministic order)
// ---------------------------------------------------------------------------
__global__ void final_kernel(const float* __restrict__ partials,
                             float* __restrict__ out) {
    if (threadIdx.x == 0 && blockIdx.x == 0) {
        double t = 0.0;
        for (int i = 0; i < NIMG; i++) t += (double)partials[i];
        out[0] = (float)(0.1 * t / 8.0);
    }
}

// ---------------------------------------------------------------------------
extern "C" void kernel_launch(void* const* d_in, const int* in_sizes, int n_in,
                              void* d_out, int out_size, void* d_ws, size_t ws_size,
                              hipStream_t stream) {
    // d_in[0] = images (UNUSED by reference), d_in[1] = model_output, d_in[2] = labels
    const float* mo = (const float*)d_in[1];
    const float* lb = (const float*)d_in[2];

    unsigned long long* maskbits = (unsigned long long*)d_ws;                 // 512 KB
    unsigned* ptsG = (unsigned*)((char*)d_ws + (size_t)NIMG * NWORDS * 8);    // 64 KB
    float* partials = (float*)((char*)d_ws + (size_t)NIMG * NWORDS * 8
                                           + (size_t)NIMG * KPTS * 4);        // 64 B
    float* out = (float*)d_out;

    lbp_kernel<<<dim3(NPIX / 256, NIMG), 256, 0, stream>>>(mo, lb, maskbits);
    select_kernel<<<NIMG, 256, 0, stream>>>(maskbits, ptsG);
    mst_kernel<<<NIMG, 64, 0, stream>>>(ptsG, partials);
    final_kernel<<<1, 64, 0, stream>>>(partials, out);
}

// Round 3
// 644.914 us; speedup vs baseline: 2.7885x; 2.7885x over previous
//
#include <hip/hip_runtime.h>

#define HH 512
#define WW 512
#define NPIX (HH * WW)          // 262144
#define NIMG 16
#define KPTS 1024
#define NWORDS (NPIX / 64)      // 4096 u64 mask words per image

// ---------------------------------------------------------------------------
// Kernel 1: binarize + uniform LBP (P=8,R=1) + ballot-pack mask bits
// ---------------------------------------------------------------------------
__global__ void lbp_kernel(const float* __restrict__ mo,
                           const float* __restrict__ lb,
                           unsigned long long* __restrict__ maskbits) {
#pragma clang fp contract(off)
    int m = blockIdx.y;                    // image 0..15: even=pred, odd=mask
    int pix = blockIdx.x * blockDim.x + threadIdx.x;   // 0..262143
    int r = pix >> 9, c = pix & 511;
    int sample = m >> 1;
    const float* img = (m & 1) ? (lb + sample * NPIX) : (mo + sample * NPIX);
    float thr = (m & 1) ? 0.5f : 0.0f;     // sigmoid(x)>0.5 <=> x>0

    float center = img[pix] > thr ? 1.0f : 0.0f;

    const float A = 0.70710678f;           // np.round(sin/cos, 8)
    const float drs[8] = {0.f, -A, -1.f, -A, 0.f,  A, 1.f, A};
    const float dcs[8] = {1.f,  A,  0.f, -A, -1.f, -A, 0.f, A};

    unsigned bb = 0u;
#pragma unroll
    for (int k = 0; k < 8; k++) {
        float rr = (float)r + drs[k];
        float cc = (float)c + dcs[k];
        float r0 = floorf(rr), c0 = floorf(cc);
        float fr = rr - r0,   fc = cc - c0;
        int r0i = (int)r0; r0i = max(0, min(HH - 1, r0i));
        int c0i = (int)c0; c0i = max(0, min(WW - 1, c0i));
        int r1i = min(HH - 1, r0i + 1);
        int c1i = min(WW - 1, c0i + 1);
        float g00 = img[r0i * WW + c0i] > thr ? 1.0f : 0.0f;
        float g01 = img[r0i * WW + c1i] > thr ? 1.0f : 0.0f;
        float g10 = img[r1i * WW + c0i] > thr ? 1.0f : 0.0f;
        float g11 = img[r1i * WW + c1i] > thr ? 1.0f : 0.0f;
        float s1 = (1.0f - fc) * g00 + fc * g01;
        float s2 = (1.0f - fc) * g10 + fc * g11;
        float smp = (1.0f - fr) * s1 + fr * s2;
        if (smp - center >= 0.0f) bb |= (1u << k);
    }
    unsigned rol = ((bb << 1) | (bb >> 7)) & 0xFFu;
    int changes = __popc(bb ^ rol);
    int s = __popc(bb);
    bool maskbit = (changes <= 2) && (s < 5);   // lbp < THR(=5)

    unsigned long long w = __ballot(maskbit);
    if ((threadIdx.x & 63) == 0)
        maskbits[m * NWORDS + (pix >> 6)] = w;
}

// ---------------------------------------------------------------------------
// Kernel 2: stable row-major compaction to K=1024 packed points per image
// pts entry: (r<<16)|c ; zero-padded (== reference's valid*coords semantics)
// ---------------------------------------------------------------------------
__global__ void select_kernel(const unsigned long long* __restrict__ maskbits,
                              unsigned* __restrict__ ptsG) {
    __shared__ unsigned sc[256];
    int m = blockIdx.x, tid = threadIdx.x;

    for (int i = tid; i < KPTS; i += 256) ptsG[m * KPTS + i] = 0u;
    __syncthreads();

    unsigned running = 0;
    for (int ch = 0; ch < 16; ch++) {
        int w = ch * 256 + tid;
        unsigned long long word = maskbits[m * NWORDS + w];
        unsigned cnt = (unsigned)__popcll(word);
        sc[tid] = cnt;
        __syncthreads();
        for (int off = 1; off < 256; off <<= 1) {
            unsigned v = (tid >= off) ? sc[tid - off] : 0u;
            __syncthreads();
            sc[tid] += v;
            __syncthreads();
        }
        unsigned incl = sc[tid];
        unsigned total = sc[255];
        unsigned rank = running + incl - cnt;   // exclusive prefix
        while (word) {
            int b = __builtin_ctzll(word);
            word &= word - 1;
            if (rank < (unsigned)KPTS) {
                unsigned p = (unsigned)(w * 64 + b);
                unsigned rr = p >> 9, cc = p & 511u;
                ptsG[m * KPTS + rank] = (rr << 16) | cc;
            }
            rank++;
        }
        running += total;
        __syncthreads();
    }
}

// ---------------------------------------------------------------------------
// Kernel 3: one single-wave block per image: Prim's MST (exact integer keys)
// key = (d2<<10)|idx : unsigned-min == argmin w/ first-index ties (d2 exact
// int < 2^19, sqrt monotone); in-tree = 0xFFFFFFFF : signed '<' in update
// == upd & ~in_tree. DPP min-reduce; select-tree + readlane broadcasts.
// ---------------------------------------------------------------------------
typedef short v2s __attribute__((ext_vector_type(2)));

__device__ __forceinline__ int dist2_packed(unsigned a, unsigned b) {
    // coords <= 511 in 16-bit halves; diffs fit i16; d2 < 2^19 exact
#if __has_builtin(__builtin_amdgcn_sdot2)
    v2s d = __builtin_bit_cast(v2s, a) - __builtin_bit_cast(v2s, b);
    return __builtin_amdgcn_sdot2(d, d, 0, false);
#else
    int dr = (int)(a >> 16) - (int)(b >> 16);
    int dc = (int)(a & 0xFFFFu) - (int)(b & 0xFFFFu);
    return __mul24(dr, dr) + __mul24(dc, dc);
#endif
}

template <int CTRL>
__device__ __forceinline__ unsigned umin_dpp(unsigned x) {
    unsigned o = (unsigned)__builtin_amdgcn_update_dpp((int)x, (int)x, CTRL,
                                                       0xf, 0xf, false);
    return o < x ? o : x;
}

#define SEL16(res, arr) do {                                              \
    unsigned a0 = b0 ? arr[1]  : arr[0];                                  \
    unsigned a1 = b0 ? arr[3]  : arr[2];                                  \
    unsigned a2 = b0 ? arr[5]  : arr[4];                                  \
    unsigned a3 = b0 ? arr[7]  : arr[6];                                  \
    unsigned a4 = b0 ? arr[9]  : arr[8];                                  \
    unsigned a5 = b0 ? arr[11] : arr[10];                                 \
    unsigned a6 = b0 ? arr[13] : arr[12];                                 \
    unsigned a7 = b0 ? arr[15] : arr[14];                                 \
    unsigned c0 = b1 ? a1 : a0;                                           \
    unsigned c1 = b1 ? a3 : a2;                                           \
    unsigned c2 = b1 ? a5 : a4;                                           \
    unsigned c3 = b1 ? a7 : a6;                                           \
    unsigned e0 = b2 ? c1 : c0;                                           \
    unsigned e1 = b2 ? c3 : c2;                                           \
    res = b3 ? e1 : e0;                                                   \
} while (0)

__global__ __launch_bounds__(64, 1) void mst_kernel(const unsigned* __restrict__ ptsG,
                                                    float* __restrict__ partials) {
    __shared__ unsigned ldsO[KPTS];
    int lane = threadIdx.x;          // 0..63
    int m = blockIdx.x;
    int partner = m ^ 1;

#pragma unroll
    for (int s = 0; s < 16; s++)
        ldsO[s * 64 + lane] = ptsG[partner * KPTS + s * 64 + lane];
    __syncthreads();

    unsigned key[16], pay[16], srcpay[16], idxc[16];

    unsigned p0 = ptsG[m * KPTS];            // self point 0 (uniform)
    unsigned o0 = ptsG[partner * KPTS];      // partner point 0 (uniform)

#pragma unroll
    for (int s = 0; s < 16; s++) {
        unsigned p = ptsG[m * KPTS + s * 64 + lane];
        pay[s] = p;                          // (r<<16)|c
        srcpay[s] = o0;                      // src init = 0 -> partner pt 0
        idxc[s] = (unsigned)(s * 64 + lane);
        int d2 = dist2_packed(p, p0);
        key[s] = ((unsigned)d2 << 10) | idxc[s];
    }
    if (lane == 0) key[0] = 0xFFFFFFFFu;     // in_tree[0] = True

    double S = 0.0;
    for (int it = 0; it < KPTS - 1; it++) {
        // ---- in-lane min tree over 16 slots (argmin lives in key bits) ----
        unsigned t[8];
#pragma unroll
        for (int s = 0; s < 8; s++)
            t[s] = key[2 * s] < key[2 * s + 1] ? key[2 * s] : key[2 * s + 1];
#pragma unroll
        for (int off = 4; off >= 1; off >>= 1) {
#pragma unroll
            for (int s = 0; s < 4; s++)
                if (s < off) t[s] = t[s] < t[s + off] ? t[s] : t[s + off];
        }
        unsigned rk = t[0];
        // ---- wave-64 min via DPP (VALU pipe, no DS latency) ----
        rk = umin_dpp<0x111>(rk);   // row_shr:1
        rk = umin_dpp<0x112>(rk);   // row_shr:2
        rk = umin_dpp<0x114>(rk);   // row_shr:4
        rk = umin_dpp<0x118>(rk);   // row_shr:8  -> lane15 of each row
        rk = umin_dpp<0x142>(rk);   // row_bcast15
        rk = umin_dpp<0x143>(rk);   // row_bcast31 -> lane63 = global min
        unsigned wk = (unsigned)__builtin_amdgcn_readlane((int)rk, 63);

        unsigned j   = wk & 1023u;
        unsigned d2p = wk >> 10;
        int wslot = (int)(j >> 6);
        int wlane = (int)(j & 63u);

        unsigned opj = ldsO[j];   // partner coords of j (uniform addr; long
                                  // latency hidden behind the update loop)

        // ---- branchless slot-select trees + lane broadcast ----
        bool b0 = (wslot & 1) != 0, b1 = (wslot & 2) != 0;
        bool b2 = (wslot & 4) != 0, b3 = (wslot & 8) != 0;
        unsigned selPay, selSrc;
        SEL16(selPay, pay);
        SEL16(selSrc, srcpay);
        unsigned pj   = (unsigned)__builtin_amdgcn_readlane((int)selPay, wlane);
        unsigned psrc = (unsigned)__builtin_amdgcn_readlane((int)selSrc, wlane);

        // ---- decrease-key update + remove j (fused, branchless) ----
        bool hit = (lane == wlane);
#pragma unroll
        for (int s = 0; s < 16; s++) {
            int d2 = dist2_packed(pay[s], pj);
            unsigned nk = ((unsigned)d2 << 10) | idxc[s];
            bool upd = (int)nk < (int)key[s];   // signed: in-tree (-1) wins
            key[s]    = upd ? nk  : key[s];
            srcpay[s] = upd ? opj : srcpay[s];
            bool kill = hit && (wslot == s);
            key[s] = kill ? 0xFFFFFFFFu : key[s];
        }

        // ---- edge contribution: (D_self[e] - D_other[e])^2 ----
        int dm2 = dist2_packed(opj, psrc);
        float Dp = __fsqrt_rn((float)d2p);
        float Dm = __fsqrt_rn((float)dm2);
        float diff = Dp - Dm;
        S += (double)diff * (double)diff;
    }
    if (lane == 0) partials[m] = (float)sqrt(S);
}

// ---------------------------------------------------------------------------
// Kernel 4: loss = 0.1 * sum(sqrt(S_m)) / 8  (deterministic order)
// ---------------------------------------------------------------------------
__global__ void final_kernel(const float* __restrict__ partials,
                             float* __restrict__ out) {
    if (threadIdx.x == 0 && blockIdx.x == 0) {
        double t = 0.0;
        for (int i = 0; i < NIMG; i++) t += (double)partials[i];
        out[0] = (float)(0.1 * t / 8.0);
    }
}

// ---------------------------------------------------------------------------
extern "C" void kernel_launch(void* const* d_in, const int* in_sizes, int n_in,
                              void* d_out, int out_size, void* d_ws, size_t ws_size,
                              hipStream_t stream) {
    const float* mo = (const float*)d_in[1];   // model_output
    const float* lb = (const float*)d_in[2];   // labels

    unsigned long long* maskbits = (unsigned long long*)d_ws;                 // 512 KB
    unsigned* ptsG = (unsigned*)((char*)d_ws + (size_t)NIMG * NWORDS * 8);    // 64 KB
    float* partials = (float*)((char*)d_ws + (size_t)NIMG * NWORDS * 8
                                           + (size_t)NIMG * KPTS * 4);        // 64 B
    float* out = (float*)d_out;

    lbp_kernel<<<dim3(NPIX / 256, NIMG), 256, 0, stream>>>(mo, lb, maskbits);
    select_kernel<<<NIMG, 256, 0, stream>>>(maskbits, ptsG);
    mst_kernel<<<NIMG, 64, 0, stream>>>(ptsG, partials);
    final_kernel<<<1, 64, 0, stream>>>(partials, out);
}

// Round 4
// 579.444 us; speedup vs baseline: 3.1036x; 1.1130x over previous
//
#include <hip/hip_runtime.h>

#define HH 512
#define WW 512
#define NPIX (HH * WW)          // 262144
#define NIMG 16
#define KPTS 1024
#define NWORDS (NPIX / 64)      // 4096 u64 mask words per image

// ---------------------------------------------------------------------------
// Kernel 1: binarize + uniform LBP (P=8,R=1) + ballot-pack mask bits
// ---------------------------------------------------------------------------
__global__ void lbp_kernel(const float* __restrict__ mo,
                           const float* __restrict__ lb,
                           unsigned long long* __restrict__ maskbits) {
#pragma clang fp contract(off)
    int m = blockIdx.y;                    // image 0..15: even=pred, odd=mask
    int pix = blockIdx.x * blockDim.x + threadIdx.x;   // 0..262143
    int r = pix >> 9, c = pix & 511;
    int sample = m >> 1;
    const float* img = (m & 1) ? (lb + sample * NPIX) : (mo + sample * NPIX);
    float thr = (m & 1) ? 0.5f : 0.0f;     // sigmoid(x)>0.5 <=> x>0

    float center = img[pix] > thr ? 1.0f : 0.0f;

    const float A = 0.70710678f;           // np.round(sin/cos, 8)
    const float drs[8] = {0.f, -A, -1.f, -A, 0.f,  A, 1.f, A};
    const float dcs[8] = {1.f,  A,  0.f, -A, -1.f, -A, 0.f, A};

    unsigned bb = 0u;
#pragma unroll
    for (int k = 0; k < 8; k++) {
        float rr = (float)r + drs[k];
        float cc = (float)c + dcs[k];
        float r0 = floorf(rr), c0 = floorf(cc);
        float fr = rr - r0,   fc = cc - c0;
        int r0i = (int)r0; r0i = max(0, min(HH - 1, r0i));
        int c0i = (int)c0; c0i = max(0, min(WW - 1, c0i));
        int r1i = min(HH - 1, r0i + 1);
        int c1i = min(WW - 1, c0i + 1);
        float g00 = img[r0i * WW + c0i] > thr ? 1.0f : 0.0f;
        float g01 = img[r0i * WW + c1i] > thr ? 1.0f : 0.0f;
        float g10 = img[r1i * WW + c0i] > thr ? 1.0f : 0.0f;
        float g11 = img[r1i * WW + c1i] > thr ? 1.0f : 0.0f;
        float s1 = (1.0f - fc) * g00 + fc * g01;
        float s2 = (1.0f - fc) * g10 + fc * g11;
        float smp = (1.0f - fr) * s1 + fr * s2;
        if (smp - center >= 0.0f) bb |= (1u << k);
    }
    unsigned rol = ((bb << 1) | (bb >> 7)) & 0xFFu;
    int changes = __popc(bb ^ rol);
    int s = __popc(bb);
    bool maskbit = (changes <= 2) && (s < 5);   // lbp < THR(=5)

    unsigned long long w = __ballot(maskbit);
    if ((threadIdx.x & 63) == 0)
        maskbits[m * NWORDS + (pix >> 6)] = w;
}

// ---------------------------------------------------------------------------
// Kernel 2: stable row-major compaction to K=1024 packed points per image
// pts entry: (r<<16)|c ; zero-padded. Two-level scan: shfl intra-wave +
// 4-entry LDS cross-wave (2 barriers/chunk instead of 16).
// ---------------------------------------------------------------------------
__global__ void select_kernel(const unsigned long long* __restrict__ maskbits,
                              unsigned* __restrict__ ptsG) {
    __shared__ unsigned swv[4];
    int m = blockIdx.x, tid = threadIdx.x;
    int lane = tid & 63, wid = tid >> 6;

    for (int i = tid; i < KPTS; i += 256) ptsG[m * KPTS + i] = 0u;
    __syncthreads();

    unsigned running = 0;
    for (int ch = 0; ch < 16; ch++) {
        int w = ch * 256 + tid;
        unsigned long long word = maskbits[m * NWORDS + w];
        unsigned cnt = (unsigned)__popcll(word);

        unsigned x = cnt;                    // intra-wave inclusive scan
#pragma unroll
        for (int d = 1; d < 64; d <<= 1) {
            unsigned y = (unsigned)__shfl_up((int)x, d, 64);
            x += (lane >= d) ? y : 0u;
        }
        if (lane == 63) swv[wid] = x;
        __syncthreads();
        unsigned woff = 0, total = 0;
#pragma unroll
        for (int ww = 0; ww < 4; ww++) {
            unsigned t = swv[ww];
            total += t;
            woff += (ww < wid) ? t : 0u;
        }
        unsigned rank = running + woff + x - cnt;   // exclusive prefix
        while (word) {
            int b = __builtin_ctzll(word);
            word &= word - 1;
            if (rank < (unsigned)KPTS) {
                unsigned p = (unsigned)(w * 64 + b);
                unsigned rr = p >> 9, cc = p & 511u;
                ptsG[m * KPTS + rank] = (rr << 16) | cc;
            }
            rank++;
        }
        running += total;
        __syncthreads();   // protect swv before next chunk
    }
}

// ---------------------------------------------------------------------------
// Kernel 3 (phase 1): single-wave Prim per image, RECORD-ONLY.
// key = (d2<<10)|idx : unsigned-min == argmin w/ first-index ties (d2 exact
// int < 2^19); in-tree key = 0xFFFFFFFF (signed -1 so update '<' never wins).
// Emits wk=(d2p<<10)|j per iteration; src recovery deferred to phase 2.
// ---------------------------------------------------------------------------
typedef short v2s __attribute__((ext_vector_type(2)));

__device__ __forceinline__ int dist2_packed(unsigned a, unsigned b) {
#if __has_builtin(__builtin_amdgcn_sdot2)
    v2s d = __builtin_bit_cast(v2s, a) - __builtin_bit_cast(v2s, b);
    return __builtin_amdgcn_sdot2(d, d, 0, false);
#else
    int dr = (int)(a >> 16) - (int)(b >> 16);
    int dc = (int)(a & 0xFFFFu) - (int)(b & 0xFFFFu);
    return __mul24(dr, dr) + __mul24(dc, dc);
#endif
}

template <int CTRL>
__device__ __forceinline__ unsigned umin_dpp(unsigned x) {
    unsigned o = (unsigned)__builtin_amdgcn_update_dpp((int)x, (int)x, CTRL,
                                                       0xf, 0xf, false);
    return o < x ? o : x;
}

__device__ __forceinline__ unsigned umin3(unsigned a, unsigned b, unsigned c) {
    unsigned t = a < b ? a : b;          // compiler fuses to v_min3_u32
    return t < c ? t : c;
}

__global__ __launch_bounds__(64, 1) void mst_kernel(const unsigned* __restrict__ ptsG,
                                                    unsigned* __restrict__ edgesG) {
    __shared__ unsigned ldsS[KPTS];
    int lane = threadIdx.x;          // 0..63
    int m = blockIdx.x;

    unsigned key[16], pay[16], idxc[16];
    unsigned p0 = ptsG[m * KPTS];    // self point 0 (uniform)

#pragma unroll
    for (int s = 0; s < 16; s++) {
        unsigned p = ptsG[m * KPTS + s * 64 + lane];
        ldsS[s * 64 + lane] = p;
        pay[s] = p;                          // (r<<16)|c
        idxc[s] = (unsigned)(s * 64 + lane);
        int d2 = dist2_packed(p, p0);
        key[s] = ((unsigned)d2 << 10) | idxc[s];
    }
    if (lane == 0) key[0] = 0xFFFFFFFFu;     // in_tree[0] = True
    __syncthreads();

    unsigned* eout = edgesG + m * KPTS;
    for (int it = 0; it < KPTS - 1; it++) {
        // ---- in-lane min over 16 slots (argmin lives in key bits) ----
        unsigned m0 = umin3(key[0], key[1], key[2]);
        unsigned m1 = umin3(key[3], key[4], key[5]);
        unsigned m2 = umin3(key[6], key[7], key[8]);
        unsigned m3 = umin3(key[9], key[10], key[11]);
        unsigned m4 = umin3(key[12], key[13], key[14]);
        unsigned ra = umin3(m0, m1, m2);
        unsigned rb = umin3(m3, m4, key[15]);
        unsigned rk = ra < rb ? ra : rb;
        // ---- wave-64 min: 4 DPP row-folds + 4 readlane + scalar min ----
        rk = umin_dpp<0x111>(rk);   // row_shr:1
        rk = umin_dpp<0x112>(rk);   // row_shr:2
        rk = umin_dpp<0x114>(rk);   // row_shr:4
        rk = umin_dpp<0x118>(rk);   // row_shr:8 -> lane15 of each 16-row
        unsigned q0 = (unsigned)__builtin_amdgcn_readlane((int)rk, 15);
        unsigned q1 = (unsigned)__builtin_amdgcn_readlane((int)rk, 31);
        unsigned q2 = (unsigned)__builtin_amdgcn_readlane((int)rk, 47);
        unsigned q3 = (unsigned)__builtin_amdgcn_readlane((int)rk, 63);
        unsigned wa = q0 < q1 ? q0 : q1;
        unsigned wb = q2 < q3 ? q2 : q3;
        unsigned wk = wa < wb ? wa : wb;     // scalar

        unsigned j = wk & 1023u;
        int wslot = (int)(j >> 6);
        int wlane = (int)(j & 63u);

        if (lane == 0) eout[it] = wk;        // record edge (fire-and-forget)

        unsigned pjp = ldsS[j];              // uniform LDS read; latency
                                             // overlaps the kill ops below
        bool hit = (lane == wlane);
        v2s pj2 = __builtin_bit_cast(v2s, pjp);

        // ---- decrease-key + remove j (branchless) ----
#pragma unroll
        for (int s = 0; s < 16; s++) {
            v2s d = __builtin_bit_cast(v2s, pay[s]) - pj2;
#if __has_builtin(__builtin_amdgcn_sdot2)
            int d2 = __builtin_amdgcn_sdot2(d, d, 0, false);
#else
            int d2 = (int)d.x * d.x + (int)d.y * d.y;
#endif
            unsigned nk = ((unsigned)d2 << 10) | idxc[s];
            key[s] = ((int)nk < (int)key[s]) ? nk : key[s];
            key[s] = (hit && (wslot == s)) ? 0xFFFFFFFFu : key[s];
        }
    }
}

// ---------------------------------------------------------------------------
// Kernel 4 (phase 2): recover src per edge + per-edge (Dp-Dm)^2.
// src[j] = earliest-extracted v with d2(v,j)==d2p (exact-int match) —
// provably identical to the reference's strict-'<' update history.
// Grid (16 groups, 16 images) x 256 thr (4 waves, 16 edges each).
// ---------------------------------------------------------------------------
__global__ void recover_kernel(const unsigned* __restrict__ ptsG,
                               const unsigned* __restrict__ edgesG,
                               float* __restrict__ contrib) {
    __shared__ unsigned sS[KPTS];
    __shared__ unsigned sO[KPTS];
    __shared__ unsigned short sT[KPTS];   // extraction time + 1 (0 = root)
    int g = blockIdx.x, m = blockIdx.y;
    int tid = threadIdx.x;
    int partner = m ^ 1;

    for (int i = tid; i < KPTS; i += 256) {
        sS[i] = ptsG[m * KPTS + i];
        sO[i] = ptsG[partner * KPTS + i];
    }
    for (int e = tid; e < KPTS - 1; e += 256) {
        unsigned wkk = edgesG[m * KPTS + e];
        sT[wkk & 1023u] = (unsigned short)(e + 1);
    }
    if (tid == 0) sT[0] = 0;
    __syncthreads();

    int lane = tid & 63, w = tid >> 6;
    for (int k = 0; k < 16; k++) {
        int e = g * 64 + w * 16 + k;
        if (e >= KPTS - 1) break;            // only e=1023 (g=15,w=3,k=15)
        unsigned wk = edgesG[m * KPTS + e];
        unsigned j = wk & 1023u;
        unsigned d2p = wk >> 10;
        unsigned pj = sS[j];
        unsigned te1 = (unsigned)(e + 1);

        unsigned best = 0xFFFFFFFFu;
#pragma unroll
        for (int i = 0; i < 16; i++) {
            int v = i * 64 + lane;
            unsigned pv = sS[v];
            int d2 = dist2_packed(pv, pj);
            unsigned tv1 = (unsigned)sT[v];
            bool qual = ((unsigned)d2 == d2p) && (tv1 < te1);
            unsigned cand = qual ? ((tv1 << 10) | (unsigned)v) : 0xFFFFFFFFu;
            best = cand < best ? cand : best;
        }
#pragma unroll
        for (int dd = 32; dd; dd >>= 1) {
            unsigned o = (unsigned)__shfl_xor((int)best, dd, 64);
            best = o < best ? o : best;
        }
        unsigned vsrc = best & 1023u;
        if (lane == 0) {
            unsigned oj = sO[j], os = sO[vsrc];
            float Dp = __fsqrt_rn((float)d2p);
            float Dm = __fsqrt_rn((float)dist2_packed(oj, os));
            float diff = Dp - Dm;
            contrib[m * (KPTS - 1) + e] = diff * diff;
        }
    }
}

// ---------------------------------------------------------------------------
// Kernel 5: per-image f64 sum (extraction order, deterministic) -> loss
// ---------------------------------------------------------------------------
__global__ void final_kernel(const float* __restrict__ contrib,
                             float* __restrict__ out) {
    __shared__ double part[NIMG];
    int t = threadIdx.x;
    if (t < NIMG) {
        double s = 0.0;
        for (int e = 0; e < KPTS - 1; e++)
            s += (double)contrib[t * (KPTS - 1) + e];
        part[t] = sqrt(s);
    }
    __syncthreads();
    if (t == 0) {
        double tot = 0.0;
        for (int i = 0; i < NIMG; i++) tot += part[i];
        out[0] = (float)(0.1 * tot / 8.0);
    }
}

// ---------------------------------------------------------------------------
// ws layout (576 KB + eps, same footprint as R3):
//   [0,512K)     maskbits (lbp->select), then DEAD:
//   [0,64K)      edgesG   (mst->recover)   — overlaps dead maskbits
//   [64K,128K)   contrib  (recover->final) — overlaps dead maskbits
//   [512K,576K)  ptsG     (select->mst/recover)
// ---------------------------------------------------------------------------
extern "C" void kernel_launch(void* const* d_in, const int* in_sizes, int n_in,
                              void* d_out, int out_size, void* d_ws, size_t ws_size,
                              hipStream_t stream) {
    const float* mo = (const float*)d_in[1];   // model_output
    const float* lb = (const float*)d_in[2];   // labels

    unsigned long long* maskbits = (unsigned long long*)d_ws;
    unsigned* edgesG = (unsigned*)d_ws;
    float* contrib = (float*)((char*)d_ws + (size_t)64 * 1024);
    unsigned* ptsG = (unsigned*)((char*)d_ws + (size_t)NIMG * NWORDS * 8);
    float* out = (float*)d_out;

    lbp_kernel<<<dim3(NPIX / 256, NIMG), 256, 0, stream>>>(mo, lb, maskbits);
    select_kernel<<<NIMG, 256, 0, stream>>>(maskbits, ptsG);
    mst_kernel<<<NIMG, 64, 0, stream>>>(ptsG, edgesG);
    recover_kernel<<<dim3(16, NIMG), 256, 0, stream>>>(ptsG, edgesG, contrib);
    final_kernel<<<1, 64, 0, stream>>>(contrib, out);
}